// Round 1
// baseline (129.558 us; speedup 1.0000x reference)
//
#include <hip/hip_runtime.h>

// Laplacian of MLP 3 -> 128(tanh) -> 64(tanh) -> 1 via Taylor jets.
//
// Exact reduction: per batch element b, with h0 = tanh(x W1^T + b1),
// s1 = 1 - h0^2:
//   P0[j]  = h0[j]                        (value path)
//   P1d[j] = s1[j] * W1[j][d], d=0..2     (first-order, per direction)
//   P2s[j] = -2 h0[j] s1[j] * sum_d W1[j][d]^2   (summed second-order)
// Then 5 dots vs W2 (64x128): z0(+b2), z1_d, z2s. Second tanh:
//   g0 = tanh(z0), s2 = 1-g0^2
//   G2[k] = s2*z2s[k] - 2 g0[k] s2[k] * (z1_0^2+z1_1^2+z1_2^2)[k]
//   out[b] = sum_k W3[k] * G2[k]          (b3 does not enter 2nd coeff)

#define BLOCK 256
constexpr int DH1 = 128;   // hidden 1
constexpr int DH2 = 64;    // hidden 2
constexpr int KH  = 32;    // half of DH2 (k-split so accumulators fit in VGPRs)

__device__ __forceinline__ float fast_tanh(float x) {
    // tanh(x) = 1 - 2/(exp(2x)+1), exp via v_exp_f32 (2^y), rcp via v_rcp_f32.
    // Saturates correctly to +/-1 for large |x|. ~1e-6 abs error.
    float e = __builtin_amdgcn_exp2f(x * 2.885390081777926814f); // 2*log2(e)
    return 1.0f - 2.0f * __builtin_amdgcn_rcpf(e + 1.0f);
}

__global__ __launch_bounds__(BLOCK, 2) void lap_kernel(
        const float* __restrict__ x,
        const float* __restrict__ W1, const float* __restrict__ b1,
        const float* __restrict__ W2, const float* __restrict__ b2,
        const float* __restrict__ W3,
        float* __restrict__ out, int B)
{
    // LDS: all reads below are wave-uniform broadcasts -> no bank conflicts.
    __shared__ float4 s_w1p[DH1];               // {W1[j][0..2], b1[j]}
    __shared__ float4 s_w2t[DH1 * (DH2 / 4)];   // transposed: [j][k/4] -> W2[k][j]
    __shared__ float  s_b2[DH2];
    __shared__ float  s_w3[DH2];

    const int t = threadIdx.x;

    if (t < DH1) {
        s_w1p[t] = make_float4(W1[t * 3 + 0], W1[t * 3 + 1], W1[t * 3 + 2], b1[t]);
    }
    if (t < DH2) {
        s_b2[t] = b2[t];
        s_w3[t] = W3[t];
    }
    {
        float* w2f = reinterpret_cast<float*>(s_w2t);
        for (int idx = t; idx < DH1 * DH2; idx += BLOCK) {
            int j = idx >> 6;      // idx / 64
            int k = idx & 63;      // idx % 64
            w2f[idx] = W2[k * DH1 + j];   // transpose into [j][k]
        }
    }
    __syncthreads();

    const int b  = blockIdx.x * BLOCK + t;
    const int bb = (b < B) ? b : 0;
    const float x0 = x[bb * 3 + 0];
    const float x1 = x[bb * 3 + 1];
    const float x2 = x[bb * 3 + 2];

    float result = 0.0f;

    #pragma unroll 1
    for (int half = 0; half < 2; ++half) {
        float accZ0[KH], accA[KH], accBv[KH], accC[KH], accS[KH];
        #pragma unroll
        for (int k = 0; k < KH; ++k) {
            accZ0[k] = 0.f; accA[k] = 0.f; accBv[k] = 0.f; accC[k] = 0.f; accS[k] = 0.f;
        }

        const float4* w2base = s_w2t + half * (KH / 4);

        #pragma unroll 1
        for (int j = 0; j < DH1; ++j) {
            const float4 w1 = s_w1p[j];
            const float pre = fmaf(x0, w1.x, fmaf(x1, w1.y, fmaf(x2, w1.z, w1.w)));
            const float h   = fast_tanh(pre);
            const float s   = 1.0f - h * h;
            const float a0  = s * w1.x;
            const float a1  = s * w1.y;
            const float a2  = s * w1.z;
            const float wsq = w1.x * w1.x + w1.y * w1.y + w1.z * w1.z;
            const float as  = -2.0f * h * s * wsq;

            const float4* wrow = w2base + j * (DH2 / 4);
            #pragma unroll
            for (int q = 0; q < KH / 4; ++q) {
                const float4 w2v = wrow[q];
                const int k0 = q * 4;
                accZ0[k0+0] = fmaf(h,  w2v.x, accZ0[k0+0]);
                accZ0[k0+1] = fmaf(h,  w2v.y, accZ0[k0+1]);
                accZ0[k0+2] = fmaf(h,  w2v.z, accZ0[k0+2]);
                accZ0[k0+3] = fmaf(h,  w2v.w, accZ0[k0+3]);
                accA [k0+0] = fmaf(a0, w2v.x, accA [k0+0]);
                accA [k0+1] = fmaf(a0, w2v.y, accA [k0+1]);
                accA [k0+2] = fmaf(a0, w2v.z, accA [k0+2]);
                accA [k0+3] = fmaf(a0, w2v.w, accA [k0+3]);
                accBv[k0+0] = fmaf(a1, w2v.x, accBv[k0+0]);
                accBv[k0+1] = fmaf(a1, w2v.y, accBv[k0+1]);
                accBv[k0+2] = fmaf(a1, w2v.z, accBv[k0+2]);
                accBv[k0+3] = fmaf(a1, w2v.w, accBv[k0+3]);
                accC [k0+0] = fmaf(a2, w2v.x, accC [k0+0]);
                accC [k0+1] = fmaf(a2, w2v.y, accC [k0+1]);
                accC [k0+2] = fmaf(a2, w2v.z, accC [k0+2]);
                accC [k0+3] = fmaf(a2, w2v.w, accC [k0+3]);
                accS [k0+0] = fmaf(as, w2v.x, accS [k0+0]);
                accS [k0+1] = fmaf(as, w2v.y, accS [k0+1]);
                accS [k0+2] = fmaf(as, w2v.z, accS [k0+2]);
                accS [k0+3] = fmaf(as, w2v.w, accS [k0+3]);
            }
        }

        const int koff = half * KH;
        #pragma unroll
        for (int k = 0; k < KH; ++k) {
            const float z0 = accZ0[k] + s_b2[koff + k];
            const float g0 = fast_tanh(z0);
            const float s2 = 1.0f - g0 * g0;
            const float qd = accA[k]*accA[k] + accBv[k]*accBv[k] + accC[k]*accC[k];
            const float G2 = s2 * fmaf(-2.0f * g0, qd, accS[k]);
            result = fmaf(s_w3[koff + k], G2, result);
        }
    }

    if (b < B) out[b] = result;
}

extern "C" void kernel_launch(void* const* d_in, const int* in_sizes, int n_in,
                              void* d_out, int out_size, void* d_ws, size_t ws_size,
                              hipStream_t stream) {
    const float* x  = (const float*)d_in[0];
    const float* W1 = (const float*)d_in[1];
    const float* b1 = (const float*)d_in[2];
    const float* W2 = (const float*)d_in[3];
    const float* b2 = (const float*)d_in[4];
    const float* W3 = (const float*)d_in[5];
    // d_in[6] = b3: only affects the 0th Taylor coefficient, not the Laplacian.
    float* out = (float*)d_out;

    const int B = in_sizes[0] / 3;
    const int grid = (B + BLOCK - 1) / BLOCK;
    lap_kernel<<<grid, BLOCK, 0, stream>>>(x, W1, b1, W2, b2, W3, out, B);
}

// Round 2
// 30.500 us; speedup vs baseline: 4.2478x; 4.2478x over previous
//
#include <hip/hip_runtime.h>

// Laplacian of MLP 3 -> 128(tanh) -> 64(tanh) -> 1 via Taylor jets,
// reformulated as 5 f16-MFMA GEMM families + VALU jet construction.
//
// Per batch element b, with h = tanh(x W1^T + b1), s = 1-h^2:
//   P0[j] = h[j]                         (value path)
//   Pd[j] = s[j]*W1[j][d], d=0..2        (first-order per direction)
//   Ps[j] = -2 h[j] s[j] * sum_d W1[j][d]^2  (summed second-order)
// z_f = P_f @ W2^T  (5 families, K=128, N=64 outputs), then
//   g0 = tanh(z0+b2), s2 = 1-g0^2
//   G2[k] = s2*zs[k] - 2 g0 s2 * (z1^2+z2^2+z3^2)[k]
//   out[b] = sum_k W3[k]*G2[k]
//
// MFMA orientation: D = A*B with A = W2 tile [16 k x 32 j] (f16, LDS,
// fragment-ordered), B = jet fragments [32 j x 16 b] built in registers.
// Both operands use the same assumed lane->k mapping, so the result is
// correct for any HW k-permutation (it cancels between A and B).
// C/D layout (HW-verified): col = lane&15 (batch), row = (lane>>4)*4+reg (k).

typedef _Float16 half8 __attribute__((ext_vector_type(8)));
typedef float f32x4 __attribute__((ext_vector_type(4)));

#define BLOCK 256
constexpr int DH1 = 128;   // hidden 1 (K of the GEMMs)
constexpr int DH2 = 64;    // hidden 2 (M of the GEMMs)

__device__ __forceinline__ float fast_tanh(float x) {
    // tanh(x) = 1 - 2/(exp(2x)+1); v_exp_f32 + v_rcp_f32, ~1e-6 abs error.
    float e = __builtin_amdgcn_exp2f(x * 2.885390081777926814f); // 2*log2(e)
    return 1.0f - 2.0f * __builtin_amdgcn_rcpf(e + 1.0f);
}

__global__ __launch_bounds__(BLOCK, 2) void lap_mfma(
        const float* __restrict__ x,
        const float* __restrict__ W1, const float* __restrict__ b1,
        const float* __restrict__ W2, const float* __restrict__ b2,
        const float* __restrict__ W3,
        float* __restrict__ out, int B)
{
    __shared__ float4 s_w1p[DH1];                         // {W1[j][0..2], b1[j]}
    __shared__ __align__(16) _Float16 s_w2f[4][4][64][8]; // [kk][m][lane][i] A-frags
    __shared__ float s_b2[DH2];
    __shared__ float s_w3[DH2];

    const int t = threadIdx.x;

    if (t < DH1)
        s_w1p[t] = make_float4(W1[t*3+0], W1[t*3+1], W1[t*3+2], b1[t]);
    if (t < DH2) { s_b2[t] = b2[t]; s_w3[t] = W3[t]; }

    // Pack W2 (64x128 row-major) into A-fragment order:
    // lane l holds A row k = m*16 + (l&15), k-slice j = kk*32 + (l>>4)*8 + i.
    for (int idx = t; idx < 4*4*64*8; idx += BLOCK) {
        const int i  = idx & 7;
        const int l  = (idx >> 3) & 63;
        const int m  = (idx >> 9) & 3;
        const int kk = idx >> 11;
        const int k  = m*16 + (l & 15);
        const int j  = kk*32 + (l >> 4)*8 + i;
        s_w2f[kk][m][l][i] = (_Float16)W2[k*DH1 + j];
    }
    __syncthreads();

    const int lane  = t & 63;
    const int wave  = t >> 6;
    const int bcol  = lane & 15;      // batch column within wave tile
    const int g     = lane >> 4;      // k-group
    const int braw  = blockIdx.x*64 + wave*16 + bcol;
    const int b     = (braw < B) ? braw : (B - 1);

    const float x0 = x[b*3+0];
    const float x1 = x[b*3+1];
    const float x2 = x[b*3+2];

    f32x4 acc[5][4];   // [family][mtile]
    #pragma unroll
    for (int f = 0; f < 5; ++f)
        #pragma unroll
        for (int m = 0; m < 4; ++m)
            acc[f][m] = (f32x4){0.f, 0.f, 0.f, 0.f};

    #pragma unroll
    for (int kk = 0; kk < 4; ++kk) {
        // --- jet construction directly into B fragments (this lane's 8 j's) ---
        half8 fb0, fb1, fb2, fb3, fb4;
        #pragma unroll
        for (int i = 0; i < 8; ++i) {
            const int j = kk*32 + g*8 + i;
            const float4 w1 = s_w1p[j];
            const float pre = fmaf(x0, w1.x, fmaf(x1, w1.y, fmaf(x2, w1.z, w1.w)));
            const float h   = fast_tanh(pre);
            const float s   = 1.0f - h*h;
            const float wsq = w1.x*w1.x + w1.y*w1.y + w1.z*w1.z;
            fb0[i] = (_Float16)h;
            fb1[i] = (_Float16)(s * w1.x);
            fb2[i] = (_Float16)(s * w1.y);
            fb3[i] = (_Float16)(s * w1.z);
            fb4[i] = (_Float16)(-2.0f * h * s * wsq);
        }
        // --- 20 MFMAs: 5 families x 4 k-tiles ---
        #pragma unroll
        for (int m = 0; m < 4; ++m) {
            const half8 fa = *(const half8*)&s_w2f[kk][m][lane][0];
            acc[0][m] = __builtin_amdgcn_mfma_f32_16x16x32_f16(fa, fb0, acc[0][m], 0, 0, 0);
            acc[1][m] = __builtin_amdgcn_mfma_f32_16x16x32_f16(fa, fb1, acc[1][m], 0, 0, 0);
            acc[2][m] = __builtin_amdgcn_mfma_f32_16x16x32_f16(fa, fb2, acc[2][m], 0, 0, 0);
            acc[3][m] = __builtin_amdgcn_mfma_f32_16x16x32_f16(fa, fb3, acc[3][m], 0, 0, 0);
            acc[4][m] = __builtin_amdgcn_mfma_f32_16x16x32_f16(fa, fb4, acc[4][m], 0, 0, 0);
        }
    }

    // --- epilogue: lane holds k = m*16 + g*4 + r for its batch column ---
    float partial = 0.0f;
    #pragma unroll
    for (int m = 0; m < 4; ++m) {
        #pragma unroll
        for (int r = 0; r < 4; ++r) {
            const int k = m*16 + g*4 + r;
            const float z0 = acc[0][m][r] + s_b2[k];
            const float g0 = fast_tanh(z0);
            const float s2 = 1.0f - g0*g0;
            const float qd = acc[1][m][r]*acc[1][m][r]
                           + acc[2][m][r]*acc[2][m][r]
                           + acc[3][m][r]*acc[3][m][r];
            const float G2 = s2 * fmaf(-2.0f * g0, qd, acc[4][m][r]);
            partial = fmaf(s_w3[k], G2, partial);
        }
    }
    // reduce the 4 k-groups (lanes l, l^16, l^32, l^48)
    partial += __shfl_xor(partial, 16);
    partial += __shfl_xor(partial, 32);

    if (g == 0 && braw < B) out[braw] = partial;
}

extern "C" void kernel_launch(void* const* d_in, const int* in_sizes, int n_in,
                              void* d_out, int out_size, void* d_ws, size_t ws_size,
                              hipStream_t stream) {
    const float* x  = (const float*)d_in[0];
    const float* W1 = (const float*)d_in[1];
    const float* b1 = (const float*)d_in[2];
    const float* W2 = (const float*)d_in[3];
    const float* b2 = (const float*)d_in[4];
    const float* W3 = (const float*)d_in[5];
    // d_in[6] = b3: does not enter the 2nd Taylor coefficient.
    float* out = (float*)d_out;

    const int B = in_sizes[0] / 3;
    const int grid = (B + 63) / 64;   // 64 batch elements per 256-thread block
    lap_mfma<<<grid, BLOCK, 0, stream>>>(x, W1, b1, W2, b2, W3, out, B);
}

// Round 3
// 28.249 us; speedup vs baseline: 4.5864x; 1.0797x over previous
//
#include <hip/hip_runtime.h>

// Laplacian of MLP 3 -> 128(tanh) -> 64(tanh) -> 1 via Taylor jets,
// as 5 f16-MFMA GEMM families + VALU jet construction.
//
// Per batch element b, with h = tanh(x W1^T + b1), s = 1-h^2:
//   P0[j] = h[j]; Pd[j] = s[j]*W1[j][d]; Ps[j] = -2 h s * sum_d W1[j][d]^2
// z_f = P_f @ W2^T (5 families, K=128, 64 outputs), then
//   g0 = tanh(z0+b2), s2 = 1-g0^2
//   G2[k] = s2*zs[k] - 2 g0 s2 * (z1^2+z2^2+z3^2)[k]
//   out[b] = sum_k W3[k]*G2[k]     (b3 never enters the 2nd coefficient)
//
// Phase A builds ALL B-fragments (jets) into registers (80 VGPR);
// phase B runs clustered MFMAs per m-tile with only 5 live accumulators
// and folds the epilogue per m. Keeps peak VGPR ~130 -> 3 waves/SIMD.
//
// MFMA orientation: D = A*B, A = W2 tile [16k x 32j] (LDS, frag-ordered),
// B = jets [32j x 16b] (regs). A and B use the same assumed lane->k map,
// so any HW k-permutation cancels. C/D: col=lane&15 (b), row=(lane>>4)*4+r (k).

typedef _Float16 half8 __attribute__((ext_vector_type(8)));
typedef float f32x4 __attribute__((ext_vector_type(4)));

#define BLOCK 256
constexpr int DH1 = 128;
constexpr int DH2 = 64;

__device__ __forceinline__ float fast_tanh(float x) {
    // tanh(x) = 1 - 2/(exp(2x)+1); v_exp_f32 + v_rcp_f32, ~1e-6 abs error.
    float e = __builtin_amdgcn_exp2f(x * 2.885390081777926814f); // 2*log2(e)
    return fmaf(-2.0f, __builtin_amdgcn_rcpf(e + 1.0f), 1.0f);
}

__global__ __launch_bounds__(BLOCK, 3) void lap_mfma(
        const float* __restrict__ x,
        const float* __restrict__ W1, const float* __restrict__ b1,
        const float* __restrict__ W2, const float* __restrict__ b2,
        const float* __restrict__ W3,
        float* __restrict__ out, int B)
{
    __shared__ float4 s_w1p[DH1];                         // {W1[j][0..2], b1[j]}
    __shared__ float  s_wq2[DH1];                         // -2*sum_d W1[j][d]^2
    __shared__ __align__(16) _Float16 s_w2f[4][4][64][8]; // [kk][m][lane][i]
    __shared__ float s_b2[DH2];
    __shared__ float s_w3[DH2];

    const int t = threadIdx.x;

    if (t < DH1) {
        const float wx = W1[t*3+0], wy = W1[t*3+1], wz = W1[t*3+2];
        s_w1p[t] = make_float4(wx, wy, wz, b1[t]);
        s_wq2[t] = -2.0f * (wx*wx + wy*wy + wz*wz);
    }
    if (t < DH2) { s_b2[t] = b2[t]; s_w3[t] = W3[t]; }

    // Pack W2 (64x128 row-major) into A-fragment order:
    // lane l holds A row k = m*16 + (l&15), k-slice j = kk*32 + (l>>4)*8 + i.
    for (int idx = t; idx < 4*4*64*8; idx += BLOCK) {
        const int i  = idx & 7;
        const int l  = (idx >> 3) & 63;
        const int m  = (idx >> 9) & 3;
        const int kk = idx >> 11;
        const int k  = m*16 + (l & 15);
        const int j  = kk*32 + (l >> 4)*8 + i;
        s_w2f[kk][m][l][i] = (_Float16)W2[k*DH1 + j];
    }
    __syncthreads();

    const int lane  = t & 63;
    const int wave  = t >> 6;
    const int bcol  = lane & 15;
    const int g     = lane >> 4;
    const int braw  = blockIdx.x*64 + wave*16 + bcol;
    const int b     = (braw < B) ? braw : (B - 1);

    const float x0 = x[b*3+0];
    const float x1 = x[b*3+1];
    const float x2 = x[b*3+2];

    // ---------------- Phase A: all jet B-fragments ----------------
    half8 F[4][5];   // [kk][family]: fully unrolled -> stays in VGPRs
    #pragma unroll
    for (int kk = 0; kk < 4; ++kk) {
        #pragma unroll
        for (int ii = 0; ii < 4; ++ii) {     // pairs of j
            float vh[2], v0[2], v1[2], v2[2], vs[2];
            #pragma unroll
            for (int u = 0; u < 2; ++u) {
                const int i = ii*2 + u;
                const int j = kk*32 + g*8 + i;
                const float4 w1 = s_w1p[j];
                const float pre = fmaf(x0, w1.x, fmaf(x1, w1.y, fmaf(x2, w1.z, w1.w)));
                const float e   = __builtin_amdgcn_exp2f(pre * 2.885390081777926814f);
                const float rr  = __builtin_amdgcn_rcpf(e + 1.0f);
                const float h   = fmaf(-2.0f, rr, 1.0f);
                const float s   = fmaf(-h, h, 1.0f);
                vh[u] = h;
                v0[u] = s * w1.x;
                v1[u] = s * w1.y;
                v2[u] = s * w1.z;
                vs[u] = (h * s) * s_wq2[j];
            }
            F[kk][0][ii*2] = (_Float16)vh[0]; F[kk][0][ii*2+1] = (_Float16)vh[1];
            F[kk][1][ii*2] = (_Float16)v0[0]; F[kk][1][ii*2+1] = (_Float16)v0[1];
            F[kk][2][ii*2] = (_Float16)v1[0]; F[kk][2][ii*2+1] = (_Float16)v1[1];
            F[kk][3][ii*2] = (_Float16)v2[0]; F[kk][3][ii*2+1] = (_Float16)v2[1];
            F[kk][4][ii*2] = (_Float16)vs[0]; F[kk][4][ii*2+1] = (_Float16)vs[1];
        }
    }

    // ---------------- Phase B: clustered MFMAs + per-m epilogue ----------------
    float partial = 0.0f;
    #pragma unroll
    for (int m = 0; m < 4; ++m) {
        f32x4 c0 = {0.f,0.f,0.f,0.f}, c1 = c0, c2 = c0, c3 = c0, c4 = c0;
        #pragma unroll
        for (int kk = 0; kk < 4; ++kk) {
            const half8 fa = *(const half8*)&s_w2f[kk][m][lane][0];
            c0 = __builtin_amdgcn_mfma_f32_16x16x32_f16(fa, F[kk][0], c0, 0, 0, 0);
            c1 = __builtin_amdgcn_mfma_f32_16x16x32_f16(fa, F[kk][1], c1, 0, 0, 0);
            c2 = __builtin_amdgcn_mfma_f32_16x16x32_f16(fa, F[kk][2], c2, 0, 0, 0);
            c3 = __builtin_amdgcn_mfma_f32_16x16x32_f16(fa, F[kk][3], c3, 0, 0, 0);
            c4 = __builtin_amdgcn_mfma_f32_16x16x32_f16(fa, F[kk][4], c4, 0, 0, 0);
        }
        #pragma unroll
        for (int r = 0; r < 4; ++r) {
            const int k = m*16 + g*4 + r;
            const float z0 = c0[r] + s_b2[k];
            const float g0 = fast_tanh(z0);
            const float s2 = fmaf(-g0, g0, 1.0f);
            const float qd = c1[r]*c1[r] + c2[r]*c2[r] + c3[r]*c3[r];
            const float G2 = s2 * fmaf(-2.0f * g0, qd, c4[r]);
            partial = fmaf(s_w3[k], G2, partial);
        }
    }

    partial += __shfl_xor(partial, 16);
    partial += __shfl_xor(partial, 32);

    if (g == 0 && braw < B) out[braw] = partial;
}

extern "C" void kernel_launch(void* const* d_in, const int* in_sizes, int n_in,
                              void* d_out, int out_size, void* d_ws, size_t ws_size,
                              hipStream_t stream) {
    const float* x  = (const float*)d_in[0];
    const float* W1 = (const float*)d_in[1];
    const float* b1 = (const float*)d_in[2];
    const float* W2 = (const float*)d_in[3];
    const float* b2 = (const float*)d_in[4];
    const float* W3 = (const float*)d_in[5];
    // d_in[6] = b3: does not enter the 2nd Taylor coefficient.
    float* out = (float*)d_out;

    const int B = in_sizes[0] / 3;
    const int grid = (B + 63) / 64;   // 64 batch elements per 256-thread block
    lap_mfma<<<grid, BLOCK, 0, stream>>>(x, W1, b1, W2, b2, W3, out, B);
}